// Round 17
// baseline (1079.424 us; speedup 1.0000x reference)
//
#include <hip/hip_runtime.h>
#include <math.h>

#define N_TOK 2048
#define NH 8
#define DH 40

// ---------------- tiled fp32 GEMM: C = A(MxK)*B(KxN) + bias, optional relu
__global__ __launch_bounds__(256) void gemm_k(const float* __restrict__ A,
    const float* __restrict__ B, const float* __restrict__ bias,
    float* __restrict__ C, int M, int N, int K, int relu)
{
    __shared__ __align__(16) float As[16][68];
    __shared__ __align__(16) float Bs[16][68];
    const int bn = blockIdx.x * 64, bm = blockIdx.y * 64;
    const int tid = threadIdx.x;
    const int tx = tid & 15, ty = tid >> 4;
    const int la_m = tid >> 2, la_k = (tid & 3) * 4;
    const int lb_k = tid >> 4, lb_n = (tid & 15) * 4;
    const int bcol = bn + lb_n;
    const int nk = K >> 4;
    float4 aq = *(const float4*)&A[(size_t)(bm + la_m) * K + la_k];
    float4 bq = make_float4(0.f, 0.f, 0.f, 0.f);
    if (bcol < N) bq = *(const float4*)&B[(size_t)lb_k * N + bcol];
    float acc[4][4] = {};
    for (int kt = 0; kt < nk; ++kt) {
        __syncthreads();
        As[la_k + 0][la_m] = aq.x; As[la_k + 1][la_m] = aq.y;
        As[la_k + 2][la_m] = aq.z; As[la_k + 3][la_m] = aq.w;
        *(float4*)&Bs[lb_k][lb_n] = bq;
        __syncthreads();
        if (kt + 1 < nk) {
            const int k0 = (kt + 1) << 4;
            aq = *(const float4*)&A[(size_t)(bm + la_m) * K + k0 + la_k];
            if (bcol < N) bq = *(const float4*)&B[(size_t)(k0 + lb_k) * N + bcol];
        }
        #pragma unroll
        for (int kk = 0; kk < 16; ++kk) {
            const float4 av = *(const float4*)&As[kk][4 * ty];
            const float4 bv = *(const float4*)&Bs[kk][4 * tx];
            acc[0][0] += av.x * bv.x; acc[0][1] += av.x * bv.y; acc[0][2] += av.x * bv.z; acc[0][3] += av.x * bv.w;
            acc[1][0] += av.y * bv.x; acc[1][1] += av.y * bv.y; acc[1][2] += av.y * bv.z; acc[1][3] += av.y * bv.w;
            acc[2][0] += av.z * bv.x; acc[2][1] += av.z * bv.y; acc[2][2] += av.z * bv.z; acc[2][3] += av.z * bv.w;
            acc[3][0] += av.w * bv.x; acc[3][1] += av.w * bv.y; acc[3][2] += av.w * bv.z; acc[3][3] += av.w * bv.w;
        }
    }
    const int c0 = bn + 4 * tx;
    if (c0 < N) {
        const float4 bz = *(const float4*)&bias[c0];
        #pragma unroll
        for (int i = 0; i < 4; ++i) {
            float4 o;
            o.x = acc[i][0] + bz.x; o.y = acc[i][1] + bz.y;
            o.z = acc[i][2] + bz.z; o.w = acc[i][3] + bz.w;
            if (relu) {
                o.x = fmaxf(o.x, 0.f); o.y = fmaxf(o.y, 0.f);
                o.z = fmaxf(o.z, 0.f); o.w = fmaxf(o.w, 0.f);
            }
            *(float4*)&C[(size_t)(bm + 4 * ty + i) * N + c0] = o;
        }
    }
}

// ---------------- fused 2-layer MLP with 160 hidden units (R16, proven)
__global__ __launch_bounds__(256) void mlp160_k(const float* __restrict__ X,
    const float* __restrict__ W1, const float* __restrict__ b1,
    const float* __restrict__ W2, const float* __restrict__ b2,
    float* __restrict__ out, int P)
{
    __shared__ __align__(16) float Xs[8][324];
    __shared__ float Hs[8][160];
    const int tid = threadIdx.x;
    const int r0 = blockIdx.x * 8;
    for (int idx = tid; idx < 8 * 80; idx += 256) {
        const int r = idx / 80, c4 = idx % 80;
        *(float4*)&Xs[r][4 * c4] = *(const float4*)&X[(size_t)(r0 + r) * 320 + 4 * c4];
    }
    __syncthreads();
    if (tid < 160) {
        const int c = tid;
        float a0 = 0.f, a1 = 0.f, a2 = 0.f, a3 = 0.f,
              a4 = 0.f, a5 = 0.f, a6 = 0.f, a7 = 0.f;
        #pragma unroll 4
        for (int k = 0; k < 320; ++k) {
            const float w = W1[(size_t)k * 160 + c];
            a0 = fmaf(Xs[0][k], w, a0); a1 = fmaf(Xs[1][k], w, a1);
            a2 = fmaf(Xs[2][k], w, a2); a3 = fmaf(Xs[3][k], w, a3);
            a4 = fmaf(Xs[4][k], w, a4); a5 = fmaf(Xs[5][k], w, a5);
            a6 = fmaf(Xs[6][k], w, a6); a7 = fmaf(Xs[7][k], w, a7);
        }
        const float bb = b1[c];
        Hs[0][c] = fmaxf(a0 + bb, 0.f); Hs[1][c] = fmaxf(a1 + bb, 0.f);
        Hs[2][c] = fmaxf(a2 + bb, 0.f); Hs[3][c] = fmaxf(a3 + bb, 0.f);
        Hs[4][c] = fmaxf(a4 + bb, 0.f); Hs[5][c] = fmaxf(a5 + bb, 0.f);
        Hs[6][c] = fmaxf(a6 + bb, 0.f); Hs[7][c] = fmaxf(a7 + bb, 0.f);
    }
    __syncthreads();
    const int r = tid >> 5, l = tid & 31;
    for (int p = 0; p < P; ++p) {
        float a = 0.f;
        for (int c = l; c < 160; c += 32)
            a = fmaf(Hs[r][c], W2[(size_t)c * P + p], a);
        #pragma unroll
        for (int off = 16; off; off >>= 1) a += __shfl_xor(a, off, 32);
        if (l == 0) out[(size_t)(r0 + r) * P + p] = a + b2[p];
    }
}

// ---------------- flash attention partials, KV-split. fp32, 8 heads, DH=40.
// 2 q-rows per thread (QT=32, 256 threads): per d-step one float2 Q-read +
// one b128 K-read feed 8 FMA -> LDS instr per FMA HALVED vs 1-row (R10).
// R10's staging swizzle kept; epilogue uses compile-time predicated select
// for BOTH ctx arrays (rule #20 — R6's runtime-indexed epilogue spilled).
#define QT 32
#define KCH 2
#define KROWS (N_TOK / KCH)
__global__ __launch_bounds__(256) void attn_part_k(const float* __restrict__ qkv,
    float* __restrict__ ctxp, float* __restrict__ msp)
{
    __shared__ __align__(8) float Qs[DH][34];
    __shared__ __align__(16) float Ks[DH][64];
    __shared__ __align__(16) float Vs[DH][64];
    const int h = blockIdx.y;
    const int q0 = blockIdx.x * QT;
    const int ch = blockIdx.z;
    const int tid = threadIdx.x;
    const int kg = tid & 15, qg = tid >> 4;   // qg in [0,16): owns rows 2qg, 2qg+1

    for (int idx = tid; idx < QT * 10; idx += 256) {
        const int r = idx / 10, qd = idx % 10;
        const float4 qq = *(const float4*)&qkv[(size_t)(q0 + r) * 960 + h * DH + 4 * qd];
        Qs[4 * qd + 0][r] = qq.x; Qs[4 * qd + 1][r] = qq.y;
        Qs[4 * qd + 2][r] = qq.z; Qs[4 * qd + 3][r] = qq.w;
    }

    float M0 = -1e30f, S0 = 0.f, M1 = -1e30f, S1 = 0.f;
    float ctx0[DH], ctx1[DH];
    #pragma unroll
    for (int d = 0; d < DH; ++d) { ctx0[d] = 0.f; ctx1[d] = 0.f; }
    const float scale = 0.15811388300841897f; // 1/sqrt(40)

    for (int t0 = ch * KROWS; t0 < (ch + 1) * KROWS; t0 += 64) {
        __syncthreads();
        for (int idx = tid; idx < 640; idx += 256) {
            const int r = idx / 10, qd = idx % 10;
            const float* base = &qkv[(size_t)(t0 + r) * 960 + h * DH];
            const float4 kq = *(const float4*)(base + 320 + 4 * qd);
            const float4 vq = *(const float4*)(base + 640 + 4 * qd);
            const int c = r ^ ((qd & 7) << 2);
            #pragma unroll
            for (int j = 0; j < 4; ++j) {
                const int d = 4 * qd + j;
                Ks[d][c] = ((const float*)&kq)[j];
                Vs[d][c] = ((const float*)&vq)[j];
            }
        }
        __syncthreads();

        float s00 = 0.f, s01 = 0.f, s02 = 0.f, s03 = 0.f;
        float s10 = 0.f, s11 = 0.f, s12 = 0.f, s13 = 0.f;
        #pragma unroll
        for (int d = 0; d < DH; ++d) {
            const float2 qv = *(const float2*)&Qs[d][2 * qg];
            const float4 kv = *(const float4*)&Ks[d][(4 * kg) ^ (((d >> 2) & 7) << 2)];
            s00 += qv.x * kv.x; s01 += qv.x * kv.y; s02 += qv.x * kv.z; s03 += qv.x * kv.w;
            s10 += qv.y * kv.x; s11 += qv.y * kv.y; s12 += qv.y * kv.z; s13 += qv.y * kv.w;
        }
        s00 *= scale; s01 *= scale; s02 *= scale; s03 *= scale;
        s10 *= scale; s11 *= scale; s12 *= scale; s13 *= scale;

        float p00, p01, p02, p03, p10, p11, p12, p13;
        {
            float tm = fmaxf(fmaxf(s00, s01), fmaxf(s02, s03));
            #pragma unroll
            for (int off = 1; off < 16; off <<= 1) tm = fmaxf(tm, __shfl_xor(tm, off, 16));
            const float Mn = fmaxf(M0, tm);
            p00 = __expf(s00 - Mn); p01 = __expf(s01 - Mn);
            p02 = __expf(s02 - Mn); p03 = __expf(s03 - Mn);
            float ps = p00 + p01 + p02 + p03;
            #pragma unroll
            for (int off = 1; off < 16; off <<= 1) ps += __shfl_xor(ps, off, 16);
            if (Mn > M0) {
                const float sc = __expf(M0 - Mn);
                S0 = S0 * sc + ps; M0 = Mn;
                #pragma unroll
                for (int d = 0; d < DH; ++d) ctx0[d] *= sc;
            } else S0 += ps;
        }
        {
            float tm = fmaxf(fmaxf(s10, s11), fmaxf(s12, s13));
            #pragma unroll
            for (int off = 1; off < 16; off <<= 1) tm = fmaxf(tm, __shfl_xor(tm, off, 16));
            const float Mn = fmaxf(M1, tm);
            p10 = __expf(s10 - Mn); p11 = __expf(s11 - Mn);
            p12 = __expf(s12 - Mn); p13 = __expf(s13 - Mn);
            float ps = p10 + p11 + p12 + p13;
            #pragma unroll
            for (int off = 1; off < 16; off <<= 1) ps += __shfl_xor(ps, off, 16);
            if (Mn > M1) {
                const float sc = __expf(M1 - Mn);
                S1 = S1 * sc + ps; M1 = Mn;
                #pragma unroll
                for (int d = 0; d < DH; ++d) ctx1[d] *= sc;
            } else S1 += ps;
        }
        #pragma unroll
        for (int d = 0; d < DH; ++d) {
            const float4 vv = *(const float4*)&Vs[d][(4 * kg) ^ (((d >> 2) & 7) << 2)];
            ctx0[d] += p00 * vv.x + p01 * vv.y + p02 * vv.z + p03 * vv.w;
            ctx1[d] += p10 * vv.x + p11 * vv.y + p12 * vv.z + p13 * vv.w;
        }
    }

    #pragma unroll
    for (int off = 1; off < 16; off <<= 1) {
        #pragma unroll
        for (int d = 0; d < DH; ++d) {
            ctx0[d] += __shfl_xor(ctx0[d], off, 16);
            ctx1[d] += __shfl_xor(ctx1[d], off, 16);
        }
    }
    // epilogue: COMPILE-TIME indices only (runtime gather would spill ctx[])
    const int qa = q0 + 2 * qg, qb = qa + 1;
    float4 o0 = make_float4(0.f, 0.f, 0.f, 0.f);
    float4 o1 = make_float4(0.f, 0.f, 0.f, 0.f);
    #pragma unroll
    for (int qq = 0; qq < 10; ++qq) {
        if (kg == qq) {
            o0.x = ctx0[4 * qq + 0]; o0.y = ctx0[4 * qq + 1];
            o0.z = ctx0[4 * qq + 2]; o0.w = ctx0[4 * qq + 3];
            o1.x = ctx1[4 * qq + 0]; o1.y = ctx1[4 * qq + 1];
            o1.z = ctx1[4 * qq + 2]; o1.w = ctx1[4 * qq + 3];
        }
    }
    if (kg < 10) {
        *(float4*)&ctxp[(size_t)((ch * N_TOK + qa) * NH + h) * DH + 4 * kg] = o0;
        *(float4*)&ctxp[(size_t)((ch * N_TOK + qb) * NH + h) * DH + 4 * kg] = o1;
    }
    if (kg == 0) {
        *(float2*)&msp[2 * ((size_t)(ch * N_TOK + qa) * NH + h)] = make_float2(M0, S0);
        *(float2*)&msp[2 * ((size_t)(ch * N_TOK + qb) * NH + h)] = make_float2(M1, S1);
    }
}

// combine partials: block per q-row, 320 threads = (h,d)
__global__ __launch_bounds__(320) void attn_comb_k(const float* __restrict__ ctxp,
    const float* __restrict__ msp, float* __restrict__ ctxo)
{
    const int q = blockIdx.x;
    const int t = threadIdx.x;          // h*40 + d
    const int h = t / DH, d = t % DH;
    const float2 ms0 = *(const float2*)&msp[2 * ((size_t)q * NH + h)];
    const float2 ms1 = *(const float2*)&msp[2 * ((size_t)(N_TOK + q) * NH + h)];
    const float c0 = ctxp[((size_t)q * NH + h) * DH + d];
    const float c1 = ctxp[((size_t)(N_TOK + q) * NH + h) * DH + d];
    const float Mx = fmaxf(ms0.x, ms1.x);
    const float w0 = __expf(ms0.x - Mx), w1 = __expf(ms1.x - Mx);
    const float S = w0 * ms0.y + w1 * ms1.y;
    ctxo[(size_t)q * 320 + t] = (w0 * c0 + w1 * c1) / S;
}

// pack (x,y,z,prob) per token into float4 (chain slot 0)
__global__ void pack_k(const float* __restrict__ s0, const float* __restrict__ prob,
                       float4* __restrict__ xslot0)
{
    const int t = blockIdx.x * 256 + threadIdx.x;
    if (t < N_TOK)
        xslot0[t] = make_float4(s0[3*t], s0[3*t+1], s0[3*t+2], prob[t]);
}

__global__ void zero_flags_k(unsigned* __restrict__ flags)
{
    const int t = threadIdx.x;
    for (int idx = t; idx < 4096; idx += 64) flags[idx] = 0u;
}

// ---------------- fused 100-step Adam refinement, cooperative persistent.
// (R13 design, stable at ~665us: write-once x-chain + store/poll barrier.)
__global__ __launch_bounds__(512) void refine_coop_k(
    float4* __restrict__ xchain, float* __restrict__ xout,
    unsigned* __restrict__ flags)
{
    __shared__ __align__(16) float4 xs4[N_TOK];
    const int tid = threadIdx.x;
    const int bid = blockIdx.x;
    const int wave = tid >> 6, lane = tid & 63;
    const int i = bid * 8 + wave;
    float m0 = 0.f, m1 = 0.f, m2 = 0.f, v0 = 0.f, v1 = 0.f, v2 = 0.f;
    float b1p = 1.f, b2p = 1.f;

    for (int t = 0; t < 100; ++t) {
        const float4* cur = xchain + ((unsigned)(t * 53) % 101u) * N_TOK;
        float4* nxt       = xchain + ((unsigned)((t + 1) * 53) % 101u) * N_TOK;
        #pragma unroll
        for (int u = 0; u < 4; ++u) {
            const int idx = tid + 512 * u;
            xs4[idx] = cur[idx];
        }
        __syncthreads();
        const float4 xi = xs4[i];
        const float ci = xi.w;
        float g0 = 0.f, g1 = 0.f, g2 = 0.f;
        #pragma unroll 8
        for (int u = 0; u < N_TOK / 64; ++u) {
            const float4 qj = xs4[lane + 64 * u];
            const float dx = xi.x - qj.x;
            const float dy = xi.y - qj.y;
            const float dz = xi.z - qj.z;
            const float d2 = fmaf(dx, dx, fmaf(dy, dy, fmaf(dz, dz, 1e-12f)));
            const float rinv = rsqrtf(d2);
            const float sc = ci + qj.w;
            float w = 0.f;
            if (d2 > 64.f)  w += sc;           // dist > 8
            if (d2 < 144.f) w -= (2.f - sc);   // dist < 12
            const float f = w * rinv;
            g0 = fmaf(f, dx, g0); g1 = fmaf(f, dy, g1); g2 = fmaf(f, dz, g2);
        }
        #pragma unroll
        for (int off = 32; off; off >>= 1) {
            g0 += __shfl_xor(g0, off, 64);
            g1 += __shfl_xor(g1, off, 64);
            g2 += __shfl_xor(g2, off, 64);
        }
        {
            const float gs = 1.f / ((float)N_TOK * (float)N_TOK);
            g0 *= gs; g1 *= gs; g2 *= gs;
            const float bw = 0.1f / (float)(N_TOK - 1);
            if (i > 0) {
                const float4 qj = xs4[i - 1];
                const float dx = xi.x - qj.x, dy = xi.y - qj.y, dz = xi.z - qj.z;
                const float b2 = fmaf(dx, dx, fmaf(dy, dy, fmaf(dz, dz, 1e-12f)));
                if (b2 > 16.f) {
                    const float f = bw * rsqrtf(b2);
                    g0 = fmaf(f, dx, g0); g1 = fmaf(f, dy, g1); g2 = fmaf(f, dz, g2);
                }
            }
            if (i < N_TOK - 1) {
                const float4 qj = xs4[i + 1];
                const float dx = xi.x - qj.x, dy = xi.y - qj.y, dz = xi.z - qj.z;
                const float b2 = fmaf(dx, dx, fmaf(dy, dy, fmaf(dz, dz, 1e-12f)));
                if (b2 > 16.f) {
                    const float f = bw * rsqrtf(b2);
                    g0 = fmaf(f, dx, g0); g1 = fmaf(f, dy, g1); g2 = fmaf(f, dz, g2);
                }
            }
            b1p *= 0.9f; b2p *= 0.999f;
            const float bc1 = 1.f - b1p, bc2 = 1.f - b2p;
            m0 = 0.9f * m0 + 0.1f * g0; v0 = 0.999f * v0 + 0.001f * g0 * g0;
            m1 = 0.9f * m1 + 0.1f * g1; v1 = 0.999f * v1 + 0.001f * g1 * g1;
            m2 = 0.9f * m2 + 0.1f * g2; v2 = 0.999f * v2 + 0.001f * g2 * g2;
            const float nx0 = xi.x - 0.01f * (m0 / bc1) / (sqrtf(v0 / bc2) + 1e-8f);
            const float nx1 = xi.y - 0.01f * (m1 / bc1) / (sqrtf(v1 / bc2) + 1e-8f);
            const float nx2 = xi.z - 0.01f * (m2 / bc1) / (sqrtf(v2 / bc2) + 1e-8f);
            if (lane == 0) {
                if (t == 99) {
                    xout[i * 3 + 0] = nx0; xout[i * 3 + 1] = nx1; xout[i * 3 + 2] = nx2;
                } else {
                    unsigned long long* p = (unsigned long long*)&nxt[i];
                    union { float2 f2; unsigned long long u; } lo, hi;
                    lo.f2 = make_float2(nx0, nx1);
                    hi.f2 = make_float2(nx2, ci);
                    __hip_atomic_store(p,     lo.u, __ATOMIC_RELAXED, __HIP_MEMORY_SCOPE_AGENT);
                    __hip_atomic_store(p + 1, hi.u, __ATOMIC_RELAXED, __HIP_MEMORY_SCOPE_AGENT);
                }
            }
        }
        if (t < 99) {
            __syncthreads();   // drains this block's x stores (vmcnt(0) per wave)
            if (tid == 0)
                __hip_atomic_store(&flags[bid * 16], (unsigned)(t + 1),
                    __ATOMIC_RELAXED, __HIP_MEMORY_SCOPE_AGENT);
            if (tid < 256) {
                while (__hip_atomic_load(&flags[tid * 16], __ATOMIC_RELAXED,
                        __HIP_MEMORY_SCOPE_AGENT) < (unsigned)(t + 1))
                    __builtin_amdgcn_s_sleep(2);
            }
            __syncthreads();
        }
    }
}

extern "C" void kernel_launch(void* const* d_in, const int* in_sizes, int n_in,
                              void* d_out, int out_size, void* d_ws, size_t ws_size,
                              hipStream_t stream)
{
    (void)in_sizes; (void)n_in; (void)out_size; (void)ws_size;
    const float* F    = (const float*)d_in[0];
    const float* bbw1 = (const float*)d_in[1];  const float* bbb1 = (const float*)d_in[2];
    const float* bbw2 = (const float*)d_in[3];  const float* bbb2 = (const float*)d_in[4];
    const float* wqkv = (const float*)d_in[9];  const float* bqkv = (const float*)d_in[10];
    const float* wo   = (const float*)d_in[11]; const float* bo   = (const float*)d_in[12];
    const float* cmw1 = (const float*)d_in[13]; const float* cmb1 = (const float*)d_in[14];
    const float* cmw2 = (const float*)d_in[15]; const float* cmb2 = (const float*)d_in[16];
    const float* rbw1 = (const float*)d_in[17]; const float* rbb1 = (const float*)d_in[18];
    const float* rbw2 = (const float*)d_in[19]; const float* rbb2 = (const float*)d_in[20];

    float* ws   = (float*)d_ws;
    float* qkv  = ws;                // 1,966,080 floats; becomes x-chain after attn
    float* h1   = qkv + 1966080;     // 655,360  } ctxp overlays h1/bf
    float* bf   = h1 + 655360;       // 655,360  }
    float* t1   = bf + 655360;       // 327,680  } msp overlays t1
    float* ctxo = t1 + 327680;       // 655,360
    float* attn = ctxo + 655360;     // 655,360
    float* c1   = attn + 655360;     // 327,680 (unused now)
    float* prob = c1 + 327680;       // 2048
    float* s0   = prob + 2048;       // 6144
    unsigned* flags = (unsigned*)(s0 + 6144);   // 4096 u32 (256 padded lines)
    float* ctxp = h1;                // partial ctx (dead h1/bf space)
    float* msp  = t1;                // partial (M,S) (dead t1 space)
    float4* xchain = (float4*)qkv;   // 101 slots x 2048 float4 = 3.3MB (< qkv)

    // backbone chain first so h1/bf/t1 are dead before attention partials
    gemm_k<<<dim3(5, 32),  256, 0, stream>>>(F,    bbw1, bbb1, h1,   2048, 320, 320, 1);
    gemm_k<<<dim3(5, 32),  256, 0, stream>>>(h1,   bbw2, bbb2, bf,   2048, 320, 320, 0);
    mlp160_k<<<256, 256, 0, stream>>>(bf, rbw1, rbb1, rbw2, rbb2, s0, 3);
    gemm_k<<<dim3(15, 32), 256, 0, stream>>>(F,    wqkv, bqkv, qkv,  2048, 960, 320, 0);
    attn_part_k<<<dim3(N_TOK / QT, NH, KCH), 256, 0, stream>>>(qkv, ctxp, msp);
    attn_comb_k<<<N_TOK, 320, 0, stream>>>(ctxp, msp, ctxo);
    gemm_k<<<dim3(5, 32),  256, 0, stream>>>(ctxo, wo,   bo,   attn, 2048, 320, 320, 0);
    mlp160_k<<<256, 256, 0, stream>>>(attn, cmw1, cmb1, cmw2, cmb2, prob, 1);
    pack_k<<<(N_TOK + 255) / 256, 256, 0, stream>>>(s0, prob, xchain);  // slot perm(0)=0
    zero_flags_k<<<1, 64, 0, stream>>>(flags);

    float4* xchainp = xchain; float* outp = (float*)d_out;
    unsigned* flagsp = flags;
    void* kargs[] = { (void*)&xchainp, (void*)&outp, (void*)&flagsp };
    hipLaunchCooperativeKernel((void*)refine_coop_k, dim3(256), dim3(512), kargs, 0, stream);
}

// Round 18
// 943.254 us; speedup vs baseline: 1.1444x; 1.1444x over previous
//
#include <hip/hip_runtime.h>
#include <math.h>

#define N_TOK 2048
#define NH 8
#define DH 40

// ---------------- tiled fp32 GEMM: C = A(MxK)*B(KxN) + bias, optional relu
__global__ __launch_bounds__(256) void gemm_k(const float* __restrict__ A,
    const float* __restrict__ B, const float* __restrict__ bias,
    float* __restrict__ C, int M, int N, int K, int relu)
{
    __shared__ __align__(16) float As[16][68];
    __shared__ __align__(16) float Bs[16][68];
    const int bn = blockIdx.x * 64, bm = blockIdx.y * 64;
    const int tid = threadIdx.x;
    const int tx = tid & 15, ty = tid >> 4;
    const int la_m = tid >> 2, la_k = (tid & 3) * 4;
    const int lb_k = tid >> 4, lb_n = (tid & 15) * 4;
    const int bcol = bn + lb_n;
    const int nk = K >> 4;
    float4 aq = *(const float4*)&A[(size_t)(bm + la_m) * K + la_k];
    float4 bq = make_float4(0.f, 0.f, 0.f, 0.f);
    if (bcol < N) bq = *(const float4*)&B[(size_t)lb_k * N + bcol];
    float acc[4][4] = {};
    for (int kt = 0; kt < nk; ++kt) {
        __syncthreads();
        As[la_k + 0][la_m] = aq.x; As[la_k + 1][la_m] = aq.y;
        As[la_k + 2][la_m] = aq.z; As[la_k + 3][la_m] = aq.w;
        *(float4*)&Bs[lb_k][lb_n] = bq;
        __syncthreads();
        if (kt + 1 < nk) {
            const int k0 = (kt + 1) << 4;
            aq = *(const float4*)&A[(size_t)(bm + la_m) * K + k0 + la_k];
            if (bcol < N) bq = *(const float4*)&B[(size_t)(k0 + lb_k) * N + bcol];
        }
        #pragma unroll
        for (int kk = 0; kk < 16; ++kk) {
            const float4 av = *(const float4*)&As[kk][4 * ty];
            const float4 bv = *(const float4*)&Bs[kk][4 * tx];
            acc[0][0] += av.x * bv.x; acc[0][1] += av.x * bv.y; acc[0][2] += av.x * bv.z; acc[0][3] += av.x * bv.w;
            acc[1][0] += av.y * bv.x; acc[1][1] += av.y * bv.y; acc[1][2] += av.y * bv.z; acc[1][3] += av.y * bv.w;
            acc[2][0] += av.z * bv.x; acc[2][1] += av.z * bv.y; acc[2][2] += av.z * bv.z; acc[2][3] += av.z * bv.w;
            acc[3][0] += av.w * bv.x; acc[3][1] += av.w * bv.y; acc[3][2] += av.w * bv.z; acc[3][3] += av.w * bv.w;
        }
    }
    const int c0 = bn + 4 * tx;
    if (c0 < N) {
        const float4 bz = *(const float4*)&bias[c0];
        #pragma unroll
        for (int i = 0; i < 4; ++i) {
            float4 o;
            o.x = acc[i][0] + bz.x; o.y = acc[i][1] + bz.y;
            o.z = acc[i][2] + bz.z; o.w = acc[i][3] + bz.w;
            if (relu) {
                o.x = fmaxf(o.x, 0.f); o.y = fmaxf(o.y, 0.f);
                o.z = fmaxf(o.z, 0.f); o.w = fmaxf(o.w, 0.f);
            }
            *(float4*)&C[(size_t)(bm + 4 * ty + i) * N + c0] = o;
        }
    }
}

// ---------------- fused 2-layer MLP with 160 hidden units (R16, proven)
__global__ __launch_bounds__(256) void mlp160_k(const float* __restrict__ X,
    const float* __restrict__ W1, const float* __restrict__ b1,
    const float* __restrict__ W2, const float* __restrict__ b2,
    float* __restrict__ out, int P)
{
    __shared__ __align__(16) float Xs[8][324];
    __shared__ float Hs[8][160];
    const int tid = threadIdx.x;
    const int r0 = blockIdx.x * 8;
    for (int idx = tid; idx < 8 * 80; idx += 256) {
        const int r = idx / 80, c4 = idx % 80;
        *(float4*)&Xs[r][4 * c4] = *(const float4*)&X[(size_t)(r0 + r) * 320 + 4 * c4];
    }
    __syncthreads();
    if (tid < 160) {
        const int c = tid;
        float a0 = 0.f, a1 = 0.f, a2 = 0.f, a3 = 0.f,
              a4 = 0.f, a5 = 0.f, a6 = 0.f, a7 = 0.f;
        #pragma unroll 4
        for (int k = 0; k < 320; ++k) {
            const float w = W1[(size_t)k * 160 + c];
            a0 = fmaf(Xs[0][k], w, a0); a1 = fmaf(Xs[1][k], w, a1);
            a2 = fmaf(Xs[2][k], w, a2); a3 = fmaf(Xs[3][k], w, a3);
            a4 = fmaf(Xs[4][k], w, a4); a5 = fmaf(Xs[5][k], w, a5);
            a6 = fmaf(Xs[6][k], w, a6); a7 = fmaf(Xs[7][k], w, a7);
        }
        const float bb = b1[c];
        Hs[0][c] = fmaxf(a0 + bb, 0.f); Hs[1][c] = fmaxf(a1 + bb, 0.f);
        Hs[2][c] = fmaxf(a2 + bb, 0.f); Hs[3][c] = fmaxf(a3 + bb, 0.f);
        Hs[4][c] = fmaxf(a4 + bb, 0.f); Hs[5][c] = fmaxf(a5 + bb, 0.f);
        Hs[6][c] = fmaxf(a6 + bb, 0.f); Hs[7][c] = fmaxf(a7 + bb, 0.f);
    }
    __syncthreads();
    const int r = tid >> 5, l = tid & 31;
    for (int p = 0; p < P; ++p) {
        float a = 0.f;
        for (int c = l; c < 160; c += 32)
            a = fmaf(Hs[r][c], W2[(size_t)c * P + p], a);
        #pragma unroll
        for (int off = 16; off; off >>= 1) a += __shfl_xor(a, off, 32);
        if (l == 0) out[(size_t)(r0 + r) * P + p] = a + b2[p];
    }
}

// ---------------- flash attention partials, KV-split (R10 structure: the
// proven local optimum — 187us, VGPR=60. R11/R15/R17 restructurings all
// regressed). ctx[] never runtime-indexed (rule #20).
#define QT 16
#define KCH 2
#define KROWS (N_TOK / KCH)
__global__ __launch_bounds__(256) void attn_part_k(const float* __restrict__ qkv,
    float* __restrict__ ctxp, float* __restrict__ msp)
{
    __shared__ float Qs[DH][17];
    __shared__ __align__(16) float Ks[DH][64];
    __shared__ __align__(16) float Vs[DH][64];
    const int h = blockIdx.y;
    const int q0 = blockIdx.x * QT;
    const int ch = blockIdx.z;
    const int tid = threadIdx.x;
    const int kg = tid & 15, q = tid >> 4;

    for (int idx = tid; idx < QT * 10; idx += 256) {
        const int r = idx / 10, qd = idx % 10;
        const float4 qq = *(const float4*)&qkv[(size_t)(q0 + r) * 960 + h * DH + 4 * qd];
        Qs[4 * qd + 0][r] = qq.x; Qs[4 * qd + 1][r] = qq.y;
        Qs[4 * qd + 2][r] = qq.z; Qs[4 * qd + 3][r] = qq.w;
    }

    float M = -1e30f, S = 0.f;
    float ctx[DH];
    #pragma unroll
    for (int d = 0; d < DH; ++d) ctx[d] = 0.f;
    const float scale = 0.15811388300841897f; // 1/sqrt(40)

    for (int t0 = ch * KROWS; t0 < (ch + 1) * KROWS; t0 += 64) {
        __syncthreads();
        for (int idx = tid; idx < 640; idx += 256) {
            const int r = idx / 10, qd = idx % 10;
            const float* base = &qkv[(size_t)(t0 + r) * 960 + h * DH];
            const float4 kq = *(const float4*)(base + 320 + 4 * qd);
            const float4 vq = *(const float4*)(base + 640 + 4 * qd);
            const int c = r ^ ((qd & 7) << 2);
            #pragma unroll
            for (int j = 0; j < 4; ++j) {
                const int d = 4 * qd + j;
                Ks[d][c] = ((const float*)&kq)[j];
                Vs[d][c] = ((const float*)&vq)[j];
            }
        }
        __syncthreads();

        float s0_ = 0.f, s1_ = 0.f, s2_ = 0.f, s3_ = 0.f;
        #pragma unroll
        for (int d = 0; d < DH; ++d) {
            const float qv = Qs[d][q];
            const float4 kv = *(const float4*)&Ks[d][(4 * kg) ^ (((d >> 2) & 7) << 2)];
            s0_ += qv * kv.x; s1_ += qv * kv.y; s2_ += qv * kv.z; s3_ += qv * kv.w;
        }
        s0_ *= scale; s1_ *= scale; s2_ *= scale; s3_ *= scale;

        float tm = fmaxf(fmaxf(s0_, s1_), fmaxf(s2_, s3_));
        #pragma unroll
        for (int off = 1; off < 16; off <<= 1) tm = fmaxf(tm, __shfl_xor(tm, off, 16));
        const float Mn = fmaxf(M, tm);
        const float p0 = __expf(s0_ - Mn), p1 = __expf(s1_ - Mn);
        const float p2 = __expf(s2_ - Mn), p3 = __expf(s3_ - Mn);
        float ps = p0 + p1 + p2 + p3;
        #pragma unroll
        for (int off = 1; off < 16; off <<= 1) ps += __shfl_xor(ps, off, 16);
        if (Mn > M) {
            const float sc = __expf(M - Mn);
            S = S * sc + ps; M = Mn;
            #pragma unroll
            for (int d = 0; d < DH; ++d) ctx[d] *= sc;
        } else S += ps;

        #pragma unroll
        for (int d = 0; d < DH; ++d) {
            const float4 vv = *(const float4*)&Vs[d][(4 * kg) ^ (((d >> 2) & 7) << 2)];
            ctx[d] += p0 * vv.x + p1 * vv.y + p2 * vv.z + p3 * vv.w;
        }
    }

    #pragma unroll
    for (int off = 1; off < 16; off <<= 1) {
        #pragma unroll
        for (int d = 0; d < DH; ++d) ctx[d] += __shfl_xor(ctx[d], off, 16);
    }
    const int qr = q0 + q;
    float4 o = make_float4(0.f, 0.f, 0.f, 0.f);
    #pragma unroll
    for (int qq = 0; qq < 10; ++qq) {
        if (kg == qq) {
            o.x = ctx[4 * qq + 0]; o.y = ctx[4 * qq + 1];
            o.z = ctx[4 * qq + 2]; o.w = ctx[4 * qq + 3];
        }
    }
    if (kg < 10)
        *(float4*)&ctxp[(size_t)((ch * N_TOK + qr) * NH + h) * DH + 4 * kg] = o;
    if (kg == 0)
        *(float2*)&msp[2 * ((size_t)(ch * N_TOK + qr) * NH + h)] = make_float2(M, S);
}

// combine partials: block per q-row, 320 threads = (h,d)
__global__ __launch_bounds__(320) void attn_comb_k(const float* __restrict__ ctxp,
    const float* __restrict__ msp, float* __restrict__ ctxo)
{
    const int q = blockIdx.x;
    const int t = threadIdx.x;          // h*40 + d
    const int h = t / DH, d = t % DH;
    const float2 ms0 = *(const float2*)&msp[2 * ((size_t)q * NH + h)];
    const float2 ms1 = *(const float2*)&msp[2 * ((size_t)(N_TOK + q) * NH + h)];
    const float c0 = ctxp[((size_t)q * NH + h) * DH + d];
    const float c1 = ctxp[((size_t)(N_TOK + q) * NH + h) * DH + d];
    const float Mx = fmaxf(ms0.x, ms1.x);
    const float w0 = __expf(ms0.x - Mx), w1 = __expf(ms1.x - Mx);
    const float S = w0 * ms0.y + w1 * ms1.y;
    ctxo[(size_t)q * 320 + t] = (w0 * c0 + w1 * c1) / S;
}

// pack (x,y,z,prob) per token into float4 (chain slot 0); block 0 also
// zeroes the barrier flags (fused to save one launch slot).
__global__ void pack_k(const float* __restrict__ s0, const float* __restrict__ prob,
                       float4* __restrict__ xslot0, unsigned* __restrict__ flags)
{
    const int t = blockIdx.x * 256 + threadIdx.x;
    if (t < N_TOK)
        xslot0[t] = make_float4(s0[3*t], s0[3*t+1], s0[3*t+2], prob[t]);
    if (blockIdx.x == 0)
        for (int idx = threadIdx.x; idx < 4096; idx += 256) flags[idx] = 0u;
}

// ---------------- fused 100-step Adam refinement, cooperative persistent.
// (R13 design, stable ~665us across R13/R15/R16: write-once x-chain —
// sc0sc1 stores to L3, plain cached reads of once-written addresses —
// + store/poll barrier on padded per-block lines with 256 independent
// per-thread pollers. R12 uncached-reload and R14 batched-poll both lost.)
__global__ __launch_bounds__(512) void refine_coop_k(
    float4* __restrict__ xchain, float* __restrict__ xout,
    unsigned* __restrict__ flags)
{
    __shared__ __align__(16) float4 xs4[N_TOK];
    const int tid = threadIdx.x;
    const int bid = blockIdx.x;
    const int wave = tid >> 6, lane = tid & 63;
    const int i = bid * 8 + wave;
    float m0 = 0.f, m1 = 0.f, m2 = 0.f, v0 = 0.f, v1 = 0.f, v2 = 0.f;
    float b1p = 1.f, b2p = 1.f;

    for (int t = 0; t < 100; ++t) {
        const float4* cur = xchain + ((unsigned)(t * 53) % 101u) * N_TOK;
        float4* nxt       = xchain + ((unsigned)((t + 1) * 53) % 101u) * N_TOK;
        #pragma unroll
        for (int u = 0; u < 4; ++u) {
            const int idx = tid + 512 * u;
            xs4[idx] = cur[idx];
        }
        __syncthreads();
        const float4 xi = xs4[i];
        const float ci = xi.w;
        float g0 = 0.f, g1 = 0.f, g2 = 0.f;
        #pragma unroll 8
        for (int u = 0; u < N_TOK / 64; ++u) {
            const float4 qj = xs4[lane + 64 * u];
            const float dx = xi.x - qj.x;
            const float dy = xi.y - qj.y;
            const float dz = xi.z - qj.z;
            const float d2 = fmaf(dx, dx, fmaf(dy, dy, fmaf(dz, dz, 1e-12f)));
            const float rinv = rsqrtf(d2);
            const float sc = ci + qj.w;
            float w = 0.f;
            if (d2 > 64.f)  w += sc;           // dist > 8
            if (d2 < 144.f) w -= (2.f - sc);   // dist < 12
            const float f = w * rinv;
            g0 = fmaf(f, dx, g0); g1 = fmaf(f, dy, g1); g2 = fmaf(f, dz, g2);
        }
        #pragma unroll
        for (int off = 32; off; off >>= 1) {
            g0 += __shfl_xor(g0, off, 64);
            g1 += __shfl_xor(g1, off, 64);
            g2 += __shfl_xor(g2, off, 64);
        }
        {
            const float gs = 1.f / ((float)N_TOK * (float)N_TOK);
            g0 *= gs; g1 *= gs; g2 *= gs;
            const float bw = 0.1f / (float)(N_TOK - 1);
            if (i > 0) {
                const float4 qj = xs4[i - 1];
                const float dx = xi.x - qj.x, dy = xi.y - qj.y, dz = xi.z - qj.z;
                const float b2 = fmaf(dx, dx, fmaf(dy, dy, fmaf(dz, dz, 1e-12f)));
                if (b2 > 16.f) {
                    const float f = bw * rsqrtf(b2);
                    g0 = fmaf(f, dx, g0); g1 = fmaf(f, dy, g1); g2 = fmaf(f, dz, g2);
                }
            }
            if (i < N_TOK - 1) {
                const float4 qj = xs4[i + 1];
                const float dx = xi.x - qj.x, dy = xi.y - qj.y, dz = xi.z - qj.z;
                const float b2 = fmaf(dx, dx, fmaf(dy, dy, fmaf(dz, dz, 1e-12f)));
                if (b2 > 16.f) {
                    const float f = bw * rsqrtf(b2);
                    g0 = fmaf(f, dx, g0); g1 = fmaf(f, dy, g1); g2 = fmaf(f, dz, g2);
                }
            }
            b1p *= 0.9f; b2p *= 0.999f;
            const float bc1 = 1.f - b1p, bc2 = 1.f - b2p;
            m0 = 0.9f * m0 + 0.1f * g0; v0 = 0.999f * v0 + 0.001f * g0 * g0;
            m1 = 0.9f * m1 + 0.1f * g1; v1 = 0.999f * v1 + 0.001f * g1 * g1;
            m2 = 0.9f * m2 + 0.1f * g2; v2 = 0.999f * v2 + 0.001f * g2 * g2;
            const float nx0 = xi.x - 0.01f * (m0 / bc1) / (sqrtf(v0 / bc2) + 1e-8f);
            const float nx1 = xi.y - 0.01f * (m1 / bc1) / (sqrtf(v1 / bc2) + 1e-8f);
            const float nx2 = xi.z - 0.01f * (m2 / bc1) / (sqrtf(v2 / bc2) + 1e-8f);
            if (lane == 0) {
                if (t == 99) {
                    xout[i * 3 + 0] = nx0; xout[i * 3 + 1] = nx1; xout[i * 3 + 2] = nx2;
                } else {
                    unsigned long long* p = (unsigned long long*)&nxt[i];
                    union { float2 f2; unsigned long long u; } lo, hi;
                    lo.f2 = make_float2(nx0, nx1);
                    hi.f2 = make_float2(nx2, ci);
                    __hip_atomic_store(p,     lo.u, __ATOMIC_RELAXED, __HIP_MEMORY_SCOPE_AGENT);
                    __hip_atomic_store(p + 1, hi.u, __ATOMIC_RELAXED, __HIP_MEMORY_SCOPE_AGENT);
                }
            }
        }
        if (t < 99) {
            __syncthreads();   // drains this block's x stores (vmcnt(0) per wave)
            if (tid == 0)
                __hip_atomic_store(&flags[bid * 16], (unsigned)(t + 1),
                    __ATOMIC_RELAXED, __HIP_MEMORY_SCOPE_AGENT);
            if (tid < 256) {
                while (__hip_atomic_load(&flags[tid * 16], __ATOMIC_RELAXED,
                        __HIP_MEMORY_SCOPE_AGENT) < (unsigned)(t + 1))
                    __builtin_amdgcn_s_sleep(2);
            }
            __syncthreads();
        }
    }
}

extern "C" void kernel_launch(void* const* d_in, const int* in_sizes, int n_in,
                              void* d_out, int out_size, void* d_ws, size_t ws_size,
                              hipStream_t stream)
{
    (void)in_sizes; (void)n_in; (void)out_size; (void)ws_size;
    const float* F    = (const float*)d_in[0];
    const float* bbw1 = (const float*)d_in[1];  const float* bbb1 = (const float*)d_in[2];
    const float* bbw2 = (const float*)d_in[3];  const float* bbb2 = (const float*)d_in[4];
    const float* wqkv = (const float*)d_in[9];  const float* bqkv = (const float*)d_in[10];
    const float* wo   = (const float*)d_in[11]; const float* bo   = (const float*)d_in[12];
    const float* cmw1 = (const float*)d_in[13]; const float* cmb1 = (const float*)d_in[14];
    const float* cmw2 = (const float*)d_in[15]; const float* cmb2 = (const float*)d_in[16];
    const float* rbw1 = (const float*)d_in[17]; const float* rbb1 = (const float*)d_in[18];
    const float* rbw2 = (const float*)d_in[19]; const float* rbb2 = (const float*)d_in[20];

    float* ws   = (float*)d_ws;
    float* qkv  = ws;                // 1,966,080 floats; becomes x-chain after attn
    float* h1   = qkv + 1966080;     // 655,360  } ctxp overlays h1/bf
    float* bf   = h1 + 655360;       // 655,360  }
    float* t1   = bf + 655360;       // 327,680  } msp overlays t1
    float* ctxo = t1 + 327680;       // 655,360
    float* attn = ctxo + 655360;     // 655,360
    float* c1   = attn + 655360;     // 327,680 (unused)
    float* prob = c1 + 327680;       // 2048
    float* s0   = prob + 2048;       // 6144
    unsigned* flags = (unsigned*)(s0 + 6144);   // 4096 u32 (256 padded lines)
    float* ctxp = h1;                // partial ctx (dead h1/bf space)
    float* msp  = t1;                // partial (M,S) (dead t1 space)
    float4* xchain = (float4*)qkv;   // 101 slots x 2048 float4 = 3.3MB (< qkv)

    // backbone chain first so h1/bf/t1 are dead before attention partials
    gemm_k<<<dim3(5, 32),  256, 0, stream>>>(F,    bbw1, bbb1, h1,   2048, 320, 320, 1);
    gemm_k<<<dim3(5, 32),  256, 0, stream>>>(h1,   bbw2, bbb2, bf,   2048, 320, 320, 0);
    mlp160_k<<<256, 256, 0, stream>>>(bf, rbw1, rbb1, rbw2, rbb2, s0, 3);
    gemm_k<<<dim3(15, 32), 256, 0, stream>>>(F,    wqkv, bqkv, qkv,  2048, 960, 320, 0);
    attn_part_k<<<dim3(N_TOK / QT, NH, KCH), 256, 0, stream>>>(qkv, ctxp, msp);
    attn_comb_k<<<N_TOK, 320, 0, stream>>>(ctxp, msp, ctxo);
    gemm_k<<<dim3(5, 32),  256, 0, stream>>>(ctxo, wo,   bo,   attn, 2048, 320, 320, 0);
    mlp160_k<<<256, 256, 0, stream>>>(attn, cmw1, cmb1, cmw2, cmb2, prob, 1);
    pack_k<<<(N_TOK + 255) / 256, 256, 0, stream>>>(s0, prob, xchain, flags);

    float4* xchainp = xchain; float* outp = (float*)d_out;
    unsigned* flagsp = flags;
    void* kargs[] = { (void*)&xchainp, (void*)&outp, (void*)&flagsp };
    hipLaunchCooperativeKernel((void*)refine_coop_k, dim3(256), dim3(512), kargs, 0, stream);
}